// Round 6
// baseline (1303.780 us; speedup 1.0000x reference)
//
#include <hip/hip_runtime.h>
#include <hip/hip_cooperative_groups.h>
#include <math.h>

namespace cg = cooperative_groups;

#define DIM 128

typedef float f32x4v __attribute__((ext_vector_type(4)));
typedef short bf16x8 __attribute__((ext_vector_type(8)));

static __device__ __forceinline__ short f2bf(float f) {
    unsigned u = __float_as_uint(f);
    unsigned r = (u + 0x7fffu + ((u >> 16) & 1u)) >> 16;   // RNE
    return (short)r;
}
static __device__ __forceinline__ float bf2f(unsigned short s) {
    return __uint_as_float(((unsigned)s) << 16);
}

// ---------------------------------------------------------------------------
// Cooperative preprocessing (grid sized for full co-residency at launch):
// P0 zero+wconv | P1 histogram | P2 bsum+norm+xconv | P3 bpre | P4 scan | P5 fill
__global__ __launch_bounds__(256) void preproc_kernel(
    const float* __restrict__ feat, const float* __restrict__ hx,
    const float* __restrict__ Wi, const float* __restrict__ Wh,
    const int* __restrict__ src, const int* __restrict__ dst,
    int* degO, int* degI, int* csrOff, int* cursor, int* srcSorted,
    int* bsum, int* bpre, float* normIf, short* Wbf, short* fh,
    int N, int E, int NB) {
    cg::grid_group grid = cg::this_grid();
    __shared__ int red[4];
    __shared__ int sp[256];
    const int b = blockIdx.x, t = threadIdx.x;
    const int gid = b * 256 + t;
    const int gsz = gridDim.x * 256;

    // P0: zero degrees (degO,degI contiguous) + weight bf16 convert
    for (int i = gid; i < 2 * N; i += gsz) degO[i] = 0;
    for (int i = gid; i < 98304; i += gsz) {
        int k = i & 127, n = (i >> 7) & 15, r = i >> 11;
        int gm = r % 6, cb = r / 6;
        const float* Wsrc = (gm < 3) ? Wi : Wh;
        int g = gm % 3;
        Wbf[i] = f2bf(Wsrc[k * 384 + g * 128 + cb * 16 + n]);
    }
    grid.sync();

    // P1: degree histogram
    for (int e = gid; e < E; e += gsz) {
        atomicAdd(&degO[src[e]], 1);
        atomicAdd(&degI[dst[e]], 1);
    }
    grid.sync();

    // P2: per-chunk sums of degI + normI + pre-scaled bf16 feathx
    if (b < NB) {
        int idx = b * 1024 + t * 4;
        int s = 0;
        for (int j = 0; j < 4; ++j) if (idx + j < N) s += degI[idx + j];
        for (int off = 32; off; off >>= 1) s += __shfl_down(s, off);
        if ((t & 63) == 0) red[t >> 6] = s;
        __syncthreads();
        if (t == 0) bsum[b] = red[0] + red[1] + red[2] + red[3];
    }
    for (int i = gid; i < N; i += gsz)
        normIf[i] = rsqrtf(fmaxf((float)degI[i], 1.0f));
    for (int u = gid; u < N * 64; u += gsz) {
        int n = u >> 6, q = u & 63;
        float ns = rsqrtf(fmaxf((float)degO[n], 1.0f));
        const float* spp = (q < 32) ? &feat[(size_t)n * 128 + q * 4]
                                    : &hx[(size_t)n * 128 + (q - 32) * 4];
        float4 v = *(const float4*)spp;
        short4 p;
        p.x = f2bf(v.x * ns); p.y = f2bf(v.y * ns);
        p.z = f2bf(v.z * ns); p.w = f2bf(v.w * ns);
        *(short4*)&fh[(size_t)n * 256 + q * 4] = p;   // q*4 == 128+(q-32)*4
    }
    grid.sync();

    // P3: block 0, wave 0 scans the <=64 chunk sums
    if (b == 0 && t < 64) {
        int own = (t < NB) ? bsum[t] : 0;
        int v = own;
        for (int off = 1; off < 64; off <<= 1) {
            int u = __shfl_up(v, off);
            if (t >= off) v += u;
        }
        if (t < NB) bpre[t] = v - own;
        if (t == 63) { csrOff[N] = v; cursor[N] = v; }
    }
    grid.sync();

    // P4: per-chunk exclusive scan -> csrOff + cursor
    if (b < NB) {
        int idx = b * 1024 + t * 4;
        int va[4];
        for (int j = 0; j < 4; ++j) va[j] = (idx + j < N) ? degI[idx + j] : 0;
        int s = va[0] + va[1] + va[2] + va[3];
        sp[t] = s;
        __syncthreads();
        for (int off = 1; off < 256; off <<= 1) {
            int u = (t >= off) ? sp[t - off] : 0;
            __syncthreads();
            sp[t] += u;
            __syncthreads();
        }
        int o = bpre[b] + sp[t] - s;
        for (int j = 0; j < 4; ++j) {
            if (idx + j < N) { csrOff[idx + j] = o; cursor[idx + j] = o; }
            o += va[j];
        }
    }
    grid.sync();

    // P5: counting-sort fill
    for (int e = gid; e < E; e += gsz) {
        int pos = atomicAdd(&cursor[dst[e]], 1);
        srcSorted[pos] = src[e];
    }
}

// ---------------------------------------------------------------------------
// Fallback path (non-cooperative), used only if cooperative launch refuses.
__global__ __launch_bounds__(256) void k_deg(const int* __restrict__ src,
                                             const int* __restrict__ dst,
                                             int* degO, int* degI, int E) {
    int e = blockIdx.x * 256 + threadIdx.x;
    if (e < E) { atomicAdd(&degO[src[e]], 1); atomicAdd(&degI[dst[e]], 1); }
}
__global__ __launch_bounds__(256) void k_bsum(const int* __restrict__ deg,
                                              int* __restrict__ bsum, int N) {
    __shared__ int red[4];
    int b = blockIdx.x, t = threadIdx.x;
    int idx = b * 1024 + t * 4;
    int s = 0;
    for (int j = 0; j < 4; ++j) if (idx + j < N) s += deg[idx + j];
    for (int off = 32; off; off >>= 1) s += __shfl_down(s, off);
    if ((t & 63) == 0) red[t >> 6] = s;
    __syncthreads();
    if (t == 0) bsum[b] = red[0] + red[1] + red[2] + red[3];
}
__global__ __launch_bounds__(64) void k_bpre(const int* __restrict__ bsum,
                                             int* __restrict__ bpre, int NB,
                                             int* csrOffN, int* cursorN) {
    int t = threadIdx.x;
    int own = (t < NB) ? bsum[t] : 0;
    int v = own;
    for (int off = 1; off < 64; off <<= 1) {
        int u = __shfl_up(v, off);
        if (t >= off) v += u;
    }
    if (t < NB) bpre[t] = v - own;
    if (t == 63) { *csrOffN = v; *cursorN = v; }
}
__global__ __launch_bounds__(256) void k_off(const int* __restrict__ deg,
                                             const int* __restrict__ bpre,
                                             int* __restrict__ csrOff,
                                             int* __restrict__ cursor, int N) {
    __shared__ int sp[256];
    int b = blockIdx.x, t = threadIdx.x;
    int idx = b * 1024 + t * 4;
    int va[4];
    for (int j = 0; j < 4; ++j) va[j] = (idx + j < N) ? deg[idx + j] : 0;
    int s = va[0] + va[1] + va[2] + va[3];
    sp[t] = s;
    __syncthreads();
    for (int off = 1; off < 256; off <<= 1) {
        int u = (t >= off) ? sp[t - off] : 0;
        __syncthreads();
        sp[t] += u;
        __syncthreads();
    }
    int o = bpre[b] + sp[t] - s;
    for (int j = 0; j < 4; ++j) {
        if (idx + j < N) { csrOff[idx + j] = o; cursor[idx + j] = o; }
        o += va[j];
    }
}
__global__ __launch_bounds__(256) void k_xcw(const float* __restrict__ feat,
                                             const float* __restrict__ hx,
                                             const float* __restrict__ Wi,
                                             const float* __restrict__ Wh,
                                             const int* __restrict__ degO,
                                             const int* __restrict__ degI,
                                             float* __restrict__ normIf,
                                             short* __restrict__ Wbf,
                                             short* __restrict__ fh, int N) {
    int i = blockIdx.x * 256 + threadIdx.x;
    int T1 = N * 64, T2 = N * 64 + N;
    if (i < T1) {
        int n = i >> 6, q = i & 63;
        float ns = rsqrtf(fmaxf((float)degO[n], 1.0f));
        const float* spp = (q < 32) ? &feat[(size_t)n * 128 + q * 4]
                                    : &hx[(size_t)n * 128 + (q - 32) * 4];
        float4 v = *(const float4*)spp;
        short4 p;
        p.x = f2bf(v.x * ns); p.y = f2bf(v.y * ns);
        p.z = f2bf(v.z * ns); p.w = f2bf(v.w * ns);
        *(short4*)&fh[(size_t)n * 256 + q * 4] = p;
    } else if (i < T2) {
        int n = i - T1;
        normIf[n] = rsqrtf(fmaxf((float)degI[n], 1.0f));
    } else if (i < T2 + 98304) {
        int w = i - T2;
        int k = w & 127, n = (w >> 7) & 15, r = w >> 11;
        int gm = r % 6, cb = r / 6;
        const float* Wsrc = (gm < 3) ? Wi : Wh;
        int g = gm % 3;
        Wbf[w] = f2bf(Wsrc[k * 384 + g * 128 + cb * 16 + n]);
    }
}
__global__ __launch_bounds__(256) void k_fill(const int* __restrict__ src,
                                              const int* __restrict__ dst,
                                              int* cursor, int* __restrict__ srcSorted,
                                              int E) {
    int e = blockIdx.x * 256 + threadIdx.x;
    if (e < E) {
        int pos = atomicAdd(&cursor[dst[e]], 1);
        srcSorted[pos] = src[e];
    }
}

// ---------------------------------------------------------------------------
// Fused gather-aggregate + bf16 MFMA GEMM + GRU gates.
// CSR slice (offsets + edge ids) staged in LDS; gather is one edge per wave,
// 8B/lane, unroll 8 -> 8 independent loads in flight per lane.
#define ECAP 1408   // mean block edges 1024, sigma 32 -> +12 sigma cap
__global__ __launch_bounds__(256, 4) void fused_kernel(
    const short* __restrict__ fh, const float* __restrict__ hx,
    const int* __restrict__ csrOff, const int* __restrict__ srcSorted,
    const float* __restrict__ normIf, const short* __restrict__ Wbf,
    const float* __restrict__ bi, const float* __restrict__ bh,
    float* __restrict__ out, int N) {
    __shared__ __align__(16) short sA[64 * 264];   // 33792 B
    __shared__ int sOff[65];                       //   260 B
    __shared__ int sE[ECAP];                       //  5632 B  -> 39684 B total

    const int tid = threadIdx.x;
    const int wv = tid >> 6, lane = tid & 63;
    const int nb = blockIdx.x;
    const int nbase = nb * 64;

    // stage CSR offsets for this block's 64 nodes (clamped at N)
    if (tid <= 64) {
        int idx = nbase + tid;
        if (idx > N) idx = N;
        sOff[tid] = csrOff[idx];
    }
    __syncthreads();
    const int blockBeg = sOff[0];
    const int nE = sOff[64] - blockBeg;
    const int staged = (nE < ECAP) ? nE : ECAP;
    for (int j = tid; j < staged; j += 256) sE[j] = srcSorted[blockBeg + j];
    __syncthreads();

    // ---- phase 1: gather pre-scaled bf16 rows; 8B/lane, 8 loads in flight ----
    const ushort4* fh4 = (const ushort4*)fh;
    const int wrb = wv * 16;
    for (int i = 0; i < 16; ++i) {
        int r = wrb + i;
        int d = nbase + r;
        float4 acc = make_float4(0.f, 0.f, 0.f, 0.f);
        if (d < N) {
            int beg = sOff[r] - blockBeg, end = sOff[r + 1] - blockBeg;
            if (end <= staged) {
                #pragma unroll 8
                for (int e = beg; e < end; ++e) {
                    int s = sE[e];                      // LDS broadcast
                    ushort4 v = fh4[(size_t)s * 64 + lane];
                    acc.x += bf2f(v.x); acc.y += bf2f(v.y);
                    acc.z += bf2f(v.z); acc.w += bf2f(v.w);
                }
            } else {                                    // overflow fallback
                for (int e = beg; e < end; ++e) {
                    int s = (e < staged) ? sE[e] : srcSorted[blockBeg + e];
                    ushort4 v = fh4[(size_t)s * 64 + lane];
                    acc.x += bf2f(v.x); acc.y += bf2f(v.y);
                    acc.z += bf2f(v.z); acc.w += bf2f(v.w);
                }
            }
            float nd = normIf[d];
            acc.x *= nd; acc.y *= nd; acc.z *= nd; acc.w *= nd;
        }
        short4 p;
        p.x = f2bf(acc.x); p.y = f2bf(acc.y);
        p.z = f2bf(acc.z); p.w = f2bf(acc.w);
        *(short4*)&sA[r * 264 + lane * 4] = p;
    }
    __syncthreads();

    // ---- phase 2: 8 col-chunks, MFMA from LDS A + L2-resident Wbf ----
    const int l15 = lane & 15, quad = lane >> 4;
    const short* aRow = &sA[(wrb + l15) * 264];

    for (int cb = 0; cb < 8; ++cb) {
        f32x4v acc[6];
        #pragma unroll
        for (int g = 0; g < 6; ++g) acc[g] = (f32x4v){0.f, 0.f, 0.f, 0.f};

        #pragma unroll
        for (int kst = 0; kst < 4; ++kst) {
            const int ko = kst * 32 + quad * 8;
            bf16x8 aLo = *(const bf16x8*)&aRow[ko];
            bf16x8 aHi = *(const bf16x8*)&aRow[128 + ko];
            const short* wb = Wbf + cb * 12288 + l15 * 128 + ko;
            #pragma unroll
            for (int g = 0; g < 3; ++g) {
                bf16x8 bI = *(const bf16x8*)&wb[g * 2048];
                acc[g] = __builtin_amdgcn_mfma_f32_16x16x32_bf16(aLo, bI, acc[g], 0, 0, 0);
                bf16x8 bH = *(const bf16x8*)&wb[(g + 3) * 2048];
                acc[g + 3] = __builtin_amdgcn_mfma_f32_16x16x32_bf16(aHi, bH, acc[g + 3], 0, 0, 0);
            }
        }

        int ocol = cb * 16 + l15;
        float bir = bi[ocol], biz = bi[128 + ocol], bin = bi[256 + ocol];
        float bhr = bh[ocol], bhz = bh[128 + ocol], bhn = bh[256 + ocol];
        #pragma unroll
        for (int reg = 0; reg < 4; ++reg) {
            int row = nbase + wrb + quad * 4 + reg;
            if (row < N) {
                float ir = acc[0][reg] + bir, iz = acc[1][reg] + biz, in_ = acc[2][reg] + bin;
                float hr = acc[3][reg] + bhr, hz = acc[4][reg] + bhz, hn = acc[5][reg] + bhn;
                float rg = 1.0f / (1.0f + __expf(-(ir + hr)));
                float zg = 1.0f / (1.0f + __expf(-(iz + hz)));
                float ng = tanhf(in_ + rg * hn);
                float hv = hx[(size_t)row * DIM + ocol];
                out[(size_t)row * DIM + ocol] = (1.0f - zg) * ng + zg * hv;
            }
        }
    }
}

// ---------------------------------------------------------------------------
extern "C" void kernel_launch(void* const* d_in, const int* in_sizes, int n_in,
                              void* d_out, int out_size, void* d_ws, size_t ws_size,
                              hipStream_t stream) {
    const float* feat = (const float*)d_in[0];
    const float* hx   = (const float*)d_in[1];
    const float* Wi   = (const float*)d_in[2];
    const float* bi   = (const float*)d_in[3];
    const float* Wh   = (const float*)d_in[4];
    const float* bh   = (const float*)d_in[5];
    const int* src    = (const int*)d_in[6];
    const int* dst    = (const int*)d_in[7];
    float* out        = (float*)d_out;

    int N = in_sizes[0] / DIM;   // 50000
    int E = in_sizes[6];         // 800000
    int NB = (N + 1023) / 1024;  // 49 (<=64 required)

    int* wsi = (int*)d_ws;
    int* degO      = wsi;                      // N (degI must follow contiguously)
    int* degI      = wsi + N;                  // N
    int* csrOff    = wsi + 2 * N;              // N+1
    int* cursor    = wsi + 3 * N + 1;          // N+1
    int* srcSorted = wsi + 4 * N + 2;          // E
    int* bsum      = wsi + 4 * N + 2 + E;      // 64
    int* bpre      = bsum + 64;                // 64
    float* normIf  = (float*)(bpre + 64);      // N
    size_t wofs = (((size_t)(5 * N + 2 + E + 192)) * 4 + 15) & ~(size_t)15;
    short* Wbf = (short*)((char*)d_ws + wofs);         // 98304 bf16
    size_t fofs = (wofs + 98304 * 2 + 15) & ~(size_t)15;
    short* fh = (short*)((char*)d_ws + fofs);          // N*256 bf16 (~25.6MB)
    // total ws: ~30.1 MB (proven-safe budget: 51.6 MB)

    // size cooperative grid for full co-residency (host-only queries: free
    // in graph replay, no stream ops)
    int dev = 0;
    hipGetDevice(&dev);
    int numCU = 0;
    hipDeviceGetAttribute(&numCU, hipDeviceAttributeMultiprocessorCount, dev);
    int bpc = 0;
    hipError_t oerr = hipOccupancyMaxActiveBlocksPerMultiprocessor(
        &bpc, preproc_kernel, 256, 0);
    if (oerr != hipSuccess || bpc < 1) bpc = 1;
    if (bpc > 8) bpc = 8;
    if (numCU < 1) numCU = 256;
    long G = (long)numCU * bpc;
    if (G > 2048) G = 2048;
    if (G < NB) G = NB;

    void* cargs[] = {&feat, &hx, &Wi, &Wh, &src, &dst, &degO, &degI, &csrOff,
                     &cursor, &srcSorted, &bsum, &bpre, &normIf, &Wbf, &fh,
                     &N, &E, &NB};
    hipError_t cerr = hipLaunchCooperativeKernel((void*)preproc_kernel,
                                                 dim3((int)G), dim3(256),
                                                 cargs, 0, stream);
    if (cerr != hipSuccess) {
        // deterministic fallback: same math, separate kernels
        hipMemsetAsync(degO, 0, (size_t)(2 * N) * sizeof(int), stream);
        k_deg<<<(E + 255) / 256, 256, 0, stream>>>(src, dst, degO, degI, E);
        k_bsum<<<NB, 256, 0, stream>>>(degI, bsum, N);
        k_bpre<<<1, 64, 0, stream>>>(bsum, bpre, NB, &csrOff[N], &cursor[N]);
        k_off<<<NB, 256, 0, stream>>>(degI, bpre, csrOff, cursor, N);
        k_xcw<<<(N * 65 + 98304 + 255) / 256, 256, 0, stream>>>(
            feat, hx, Wi, Wh, degO, degI, normIf, Wbf, fh, N);
        k_fill<<<(E + 255) / 256, 256, 0, stream>>>(src, dst, cursor, srcSorted, E);
    }

    fused_kernel<<<(N + 63) / 64, 256, 0, stream>>>(
        fh, hx, csrOff, srcSorted, normIf, Wbf, bi, bh, out, N);
}

// Round 7
// 398.930 us; speedup vs baseline: 3.2682x; 3.2682x over previous
//
#include <hip/hip_runtime.h>
#include <math.h>

#define DIM 128

typedef float f32x4v __attribute__((ext_vector_type(4)));
typedef short bf16x8 __attribute__((ext_vector_type(8)));

static __device__ __forceinline__ short f2bf(float f) {
    unsigned u = __float_as_uint(f);
    unsigned r = (u + 0x7fffu + ((u >> 16) & 1u)) >> 16;   // RNE
    return (short)r;
}
static __device__ __forceinline__ float bf2f(unsigned short s) {
    return __uint_as_float(((unsigned)s) << 16);
}

// ---------------------------------------------------------------------------
// K1: integer degree histogram (both directions).
__global__ __launch_bounds__(256) void k_deg(const int* __restrict__ src,
                                             const int* __restrict__ dst,
                                             int* degO, int* degI, int E) {
    int e = blockIdx.x * 256 + threadIdx.x;
    if (e < E) { atomicAdd(&degO[src[e]], 1); atomicAdd(&degI[dst[e]], 1); }
}

// K2: per-1024-chunk sums of degI.
__global__ __launch_bounds__(256) void k_bsum(const int* __restrict__ deg,
                                              int* __restrict__ bsum, int N) {
    __shared__ int red[4];
    int b = blockIdx.x, t = threadIdx.x;
    int idx = b * 1024 + t * 4;
    int s = 0;
    for (int j = 0; j < 4; ++j) if (idx + j < N) s += deg[idx + j];
    for (int off = 32; off; off >>= 1) s += __shfl_down(s, off);
    if ((t & 63) == 0) red[t >> 6] = s;
    __syncthreads();
    if (t == 0) bsum[b] = red[0] + red[1] + red[2] + red[3];
}

// K3: per-chunk exclusive scan -> csrOff + cursor. Each block re-derives its
// chunk prefix from bsum with one wave shuffle-scan (folds old k_bpre in).
__global__ __launch_bounds__(256) void k_off(const int* __restrict__ deg,
                                             const int* __restrict__ bsum,
                                             int* __restrict__ csrOff,
                                             int* __restrict__ cursor,
                                             int N, int NB) {
    __shared__ int sp[256];
    __shared__ int sbase;
    int b = blockIdx.x, t = threadIdx.x;
    if (t < 64) {                      // wave 0: scan the <=64 chunk sums
        int own = (t < NB) ? bsum[t] : 0;
        int v = own;
        for (int off = 1; off < 64; off <<= 1) {
            int u = __shfl_up(v, off);
            if (t >= off) v += u;
        }
        if (t == b) sbase = v - own;   // exclusive prefix for this chunk
        if (b == 0 && t == NB - 1) { csrOff[N] = v; cursor[N] = v; }
    }
    __syncthreads();
    int idx = b * 1024 + t * 4;
    int va[4];
    for (int j = 0; j < 4; ++j) va[j] = (idx + j < N) ? deg[idx + j] : 0;
    int s = va[0] + va[1] + va[2] + va[3];
    sp[t] = s;
    __syncthreads();
    for (int off = 1; off < 256; off <<= 1) {
        int u = (t >= off) ? sp[t - off] : 0;
        __syncthreads();
        sp[t] += u;
        __syncthreads();
    }
    int o = sbase + sp[t] - s;
    for (int j = 0; j < 4; ++j) {
        if (idx + j < N) { csrOff[idx + j] = o; cursor[idx + j] = o; }
        o += va[j];
    }
}

// K4: merged normI + pre-scaled bf16 feat/hx + bf16 weight convert.
__global__ __launch_bounds__(256) void k_xcw(const float* __restrict__ feat,
                                             const float* __restrict__ hx,
                                             const float* __restrict__ Wi,
                                             const float* __restrict__ Wh,
                                             const int* __restrict__ degO,
                                             const int* __restrict__ degI,
                                             float* __restrict__ normIf,
                                             short* __restrict__ Wbf,
                                             short* __restrict__ fh, int N) {
    int i = blockIdx.x * 256 + threadIdx.x;
    int T1 = N * 64, T2 = N * 64 + N;
    if (i < T1) {
        int n = i >> 6, q = i & 63;
        float ns = rsqrtf(fmaxf((float)degO[n], 1.0f));
        const float* spp = (q < 32) ? &feat[(size_t)n * 128 + q * 4]
                                    : &hx[(size_t)n * 128 + (q - 32) * 4];
        float4 v = *(const float4*)spp;
        short4 p;
        p.x = f2bf(v.x * ns); p.y = f2bf(v.y * ns);
        p.z = f2bf(v.z * ns); p.w = f2bf(v.w * ns);
        *(short4*)&fh[(size_t)n * 256 + q * 4] = p;   // q*4 == 128+(q-32)*4
    } else if (i < T2) {
        int n = i - T1;
        normIf[n] = rsqrtf(fmaxf((float)degI[n], 1.0f));
    } else if (i < T2 + 98304) {
        int w = i - T2;
        int k = w & 127, n = (w >> 7) & 15, r = w >> 11;
        int gm = r % 6, cb = r / 6;
        const float* Wsrc = (gm < 3) ? Wi : Wh;
        int g = gm % 3;
        Wbf[w] = f2bf(Wsrc[k * 384 + g * 128 + cb * 16 + n]);
    }
}

// K5: counting-sort fill: srcSorted grouped by dst.
__global__ __launch_bounds__(256) void k_fill(const int* __restrict__ src,
                                              const int* __restrict__ dst,
                                              int* cursor, int* __restrict__ srcSorted,
                                              int E) {
    int e = blockIdx.x * 256 + threadIdx.x;
    if (e < E) {
        int pos = atomicAdd(&cursor[dst[e]], 1);
        srcSorted[pos] = src[e];
    }
}

// ---------------------------------------------------------------------------
// K6: fused gather-aggregate + bf16 MFMA GEMM + GRU gates (R4 structure;
// only delta: unroll 4 -> 8 for more loads in flight).
__global__ __launch_bounds__(256, 4) void fused_kernel(
    const short* __restrict__ fh, const float* __restrict__ hx,
    const int* __restrict__ csrOff, const int* __restrict__ srcSorted,
    const float* __restrict__ normIf, const short* __restrict__ Wbf,
    const float* __restrict__ bi, const float* __restrict__ bh,
    float* __restrict__ out, int N) {
    __shared__ __align__(16) short sA[64 * 264];

    const int tid = threadIdx.x;
    const int wv = tid >> 6, lane = tid & 63;
    const int nb = blockIdx.x;
    const ushort4* fh4 = (const ushort4*)fh;
    const int wrb = wv * 16;

    // ---- phase 1: gather pre-scaled bf16 rows; one 8B load/lane/edge ----
    for (int i = 0; i < 16; ++i) {
        int r = wrb + i;
        int d = nb * 64 + r;
        float4 acc = make_float4(0.f, 0.f, 0.f, 0.f);
        if (d < N) {
            int beg = csrOff[d], end = csrOff[d + 1];
            #pragma unroll 8
            for (int e = beg; e < end; ++e) {
                int s = srcSorted[e];
                ushort4 v = fh4[(size_t)s * 64 + lane];
                acc.x += bf2f(v.x); acc.y += bf2f(v.y);
                acc.z += bf2f(v.z); acc.w += bf2f(v.w);
            }
            float nd = normIf[d];
            acc.x *= nd; acc.y *= nd; acc.z *= nd; acc.w *= nd;
        }
        short4 p;
        p.x = f2bf(acc.x); p.y = f2bf(acc.y);
        p.z = f2bf(acc.z); p.w = f2bf(acc.w);
        *(short4*)&sA[r * 264 + lane * 4] = p;
    }
    __syncthreads();

    // ---- phase 2: 8 col-chunks, MFMA from LDS A + L2-resident Wbf ----
    const int l15 = lane & 15, quad = lane >> 4;
    const short* aRow = &sA[(wrb + l15) * 264];

    for (int cb = 0; cb < 8; ++cb) {
        f32x4v acc[6];
        #pragma unroll
        for (int g = 0; g < 6; ++g) acc[g] = (f32x4v){0.f, 0.f, 0.f, 0.f};

        #pragma unroll
        for (int kst = 0; kst < 4; ++kst) {
            const int ko = kst * 32 + quad * 8;
            bf16x8 aLo = *(const bf16x8*)&aRow[ko];
            bf16x8 aHi = *(const bf16x8*)&aRow[128 + ko];
            const short* wb = Wbf + cb * 12288 + l15 * 128 + ko;
            #pragma unroll
            for (int g = 0; g < 3; ++g) {
                bf16x8 bI = *(const bf16x8*)&wb[g * 2048];
                acc[g] = __builtin_amdgcn_mfma_f32_16x16x32_bf16(aLo, bI, acc[g], 0, 0, 0);
                bf16x8 bH = *(const bf16x8*)&wb[(g + 3) * 2048];
                acc[g + 3] = __builtin_amdgcn_mfma_f32_16x16x32_bf16(aHi, bH, acc[g + 3], 0, 0, 0);
            }
        }

        int ocol = cb * 16 + l15;
        float bir = bi[ocol], biz = bi[128 + ocol], bin = bi[256 + ocol];
        float bhr = bh[ocol], bhz = bh[128 + ocol], bhn = bh[256 + ocol];
        #pragma unroll
        for (int reg = 0; reg < 4; ++reg) {
            int row = nb * 64 + wrb + quad * 4 + reg;
            if (row < N) {
                float ir = acc[0][reg] + bir, iz = acc[1][reg] + biz, in_ = acc[2][reg] + bin;
                float hr = acc[3][reg] + bhr, hz = acc[4][reg] + bhz, hn = acc[5][reg] + bhn;
                float rg = 1.0f / (1.0f + __expf(-(ir + hr)));
                float zg = 1.0f / (1.0f + __expf(-(iz + hz)));
                float ng = tanhf(in_ + rg * hn);
                float hv = hx[(size_t)row * DIM + ocol];
                out[(size_t)row * DIM + ocol] = (1.0f - zg) * ng + zg * hv;
            }
        }
    }
}

// ---------------------------------------------------------------------------
extern "C" void kernel_launch(void* const* d_in, const int* in_sizes, int n_in,
                              void* d_out, int out_size, void* d_ws, size_t ws_size,
                              hipStream_t stream) {
    const float* feat = (const float*)d_in[0];
    const float* hx   = (const float*)d_in[1];
    const float* Wi   = (const float*)d_in[2];
    const float* bi   = (const float*)d_in[3];
    const float* Wh   = (const float*)d_in[4];
    const float* bh   = (const float*)d_in[5];
    const int* src    = (const int*)d_in[6];
    const int* dst    = (const int*)d_in[7];
    float* out        = (float*)d_out;

    int N = in_sizes[0] / DIM;   // 50000
    int E = in_sizes[6];         // 800000
    int NB = (N + 1023) / 1024;  // 49 (<=64 required by the wave scan)

    int* wsi = (int*)d_ws;
    int* degO      = wsi;                      // N (degI contiguous after)
    int* degI      = wsi + N;                  // N
    int* csrOff    = wsi + 2 * N;              // N+1
    int* cursor    = wsi + 3 * N + 1;          // N+1
    int* srcSorted = wsi + 4 * N + 2;          // E
    int* bsum      = wsi + 4 * N + 2 + E;      // 64
    float* normIf  = (float*)(bsum + 128);     // N
    size_t wofs = (((size_t)(5 * N + 2 + E + 192)) * 4 + 15) & ~(size_t)15;
    short* Wbf = (short*)((char*)d_ws + wofs);         // 98304 bf16
    size_t fofs = (wofs + 98304 * 2 + 15) & ~(size_t)15;
    short* fh = (short*)((char*)d_ws + fofs);          // N*256 bf16 (~25.6MB)
    // total ws: ~30.1 MB (proven-safe budget: 51.6 MB)

    hipMemsetAsync(degO, 0, (size_t)(2 * N) * sizeof(int), stream);
    k_deg<<<(E + 255) / 256, 256, 0, stream>>>(src, dst, degO, degI, E);
    k_bsum<<<NB, 256, 0, stream>>>(degI, bsum, N);
    k_off<<<NB, 256, 0, stream>>>(degI, bsum, csrOff, cursor, N, NB);
    k_xcw<<<(N * 65 + 98304 + 255) / 256, 256, 0, stream>>>(
        feat, hx, Wi, Wh, degO, degI, normIf, Wbf, fh, N);
    k_fill<<<(E + 255) / 256, 256, 0, stream>>>(src, dst, cursor, srcSorted, E);

    fused_kernel<<<(N + 63) / 64, 256, 0, stream>>>(
        fh, hx, csrOff, srcSorted, normIf, Wbf, bi, bh, out, N);
}

// Round 8
// 390.386 us; speedup vs baseline: 3.3397x; 1.0219x over previous
//
#include <hip/hip_runtime.h>
#include <math.h>

#define DIM 128

typedef float f32x4v __attribute__((ext_vector_type(4)));
typedef short bf16x8 __attribute__((ext_vector_type(8)));

static __device__ __forceinline__ short f2bf(float f) {
    unsigned u = __float_as_uint(f);
    unsigned r = (u + 0x7fffu + ((u >> 16) & 1u)) >> 16;   // RNE
    return (short)r;
}
static __device__ __forceinline__ float bf2f(unsigned short s) {
    return __uint_as_float(((unsigned)s) << 16);
}

// ---------------------------------------------------------------------------
// K1: integer degree histogram (both directions).
__global__ __launch_bounds__(256) void k_deg(const int* __restrict__ src,
                                             const int* __restrict__ dst,
                                             int* degO, int* degI, int E) {
    int e = blockIdx.x * 256 + threadIdx.x;
    if (e < E) { atomicAdd(&degO[src[e]], 1); atomicAdd(&degI[dst[e]], 1); }
}

// K2: per-1024-chunk sums of degI.
__global__ __launch_bounds__(256) void k_bsum(const int* __restrict__ deg,
                                              int* __restrict__ bsum, int N) {
    __shared__ int red[4];
    int b = blockIdx.x, t = threadIdx.x;
    int idx = b * 1024 + t * 4;
    int s = 0;
    for (int j = 0; j < 4; ++j) if (idx + j < N) s += deg[idx + j];
    for (int off = 32; off; off >>= 1) s += __shfl_down(s, off);
    if ((t & 63) == 0) red[t >> 6] = s;
    __syncthreads();
    if (t == 0) bsum[b] = red[0] + red[1] + red[2] + red[3];
}

// K3: per-chunk exclusive scan -> csrOff + cursor (bpre folded in: wave 0
// re-scans the <=64 chunk sums).
__global__ __launch_bounds__(256) void k_off(const int* __restrict__ deg,
                                             const int* __restrict__ bsum,
                                             int* __restrict__ csrOff,
                                             int* __restrict__ cursor,
                                             int N, int NB) {
    __shared__ int sp[256];
    __shared__ int sbase;
    int b = blockIdx.x, t = threadIdx.x;
    if (t < 64) {
        int own = (t < NB) ? bsum[t] : 0;
        int v = own;
        for (int off = 1; off < 64; off <<= 1) {
            int u = __shfl_up(v, off);
            if (t >= off) v += u;
        }
        if (t == b) sbase = v - own;
        if (b == 0 && t == NB - 1) { csrOff[N] = v; cursor[N] = v; }
    }
    __syncthreads();
    int idx = b * 1024 + t * 4;
    int va[4];
    for (int j = 0; j < 4; ++j) va[j] = (idx + j < N) ? deg[idx + j] : 0;
    int s = va[0] + va[1] + va[2] + va[3];
    sp[t] = s;
    __syncthreads();
    for (int off = 1; off < 256; off <<= 1) {
        int u = (t >= off) ? sp[t - off] : 0;
        __syncthreads();
        sp[t] += u;
        __syncthreads();
    }
    int o = sbase + sp[t] - s;
    for (int j = 0; j < 4; ++j) {
        if (idx + j < N) { csrOff[idx + j] = o; cursor[idx + j] = o; }
        o += va[j];
    }
}

// K4: merged normI + pre-scaled bf16 feat/hx + bf16 weight convert.
__global__ __launch_bounds__(256) void k_xcw(const float* __restrict__ feat,
                                             const float* __restrict__ hx,
                                             const float* __restrict__ Wi,
                                             const float* __restrict__ Wh,
                                             const int* __restrict__ degO,
                                             const int* __restrict__ degI,
                                             float* __restrict__ normIf,
                                             short* __restrict__ Wbf,
                                             short* __restrict__ fh, int N) {
    int i = blockIdx.x * 256 + threadIdx.x;
    int T1 = N * 64, T2 = N * 64 + N;
    if (i < T1) {
        int n = i >> 6, q = i & 63;
        float ns = rsqrtf(fmaxf((float)degO[n], 1.0f));
        const float* spp = (q < 32) ? &feat[(size_t)n * 128 + q * 4]
                                    : &hx[(size_t)n * 128 + (q - 32) * 4];
        float4 v = *(const float4*)spp;
        short4 p;
        p.x = f2bf(v.x * ns); p.y = f2bf(v.y * ns);
        p.z = f2bf(v.z * ns); p.w = f2bf(v.w * ns);
        *(short4*)&fh[(size_t)n * 256 + q * 4] = p;   // q*4 == 128+(q-32)*4
    } else if (i < T2) {
        int n = i - T1;
        normIf[n] = rsqrtf(fmaxf((float)degI[n], 1.0f));
    } else if (i < T2 + 98304) {
        int w = i - T2;
        int k = w & 127, n = (w >> 7) & 15, r = w >> 11;
        int gm = r % 6, cb = r / 6;
        const float* Wsrc = (gm < 3) ? Wi : Wh;
        int g = gm % 3;
        Wbf[w] = f2bf(Wsrc[k * 384 + g * 128 + cb * 16 + n]);
    }
}

// K5: counting-sort fill: srcSorted grouped by dst.
__global__ __launch_bounds__(256) void k_fill(const int* __restrict__ src,
                                              const int* __restrict__ dst,
                                              int* cursor, int* __restrict__ srcSorted,
                                              int E) {
    int e = blockIdx.x * 256 + threadIdx.x;
    if (e < E) {
        int pos = atomicAdd(&cursor[dst[e]], 1);
        srcSorted[pos] = src[e];
    }
}

// ---------------------------------------------------------------------------
// K6: gather-aggregate. One wave per dst node, no LDS -> 32 waves/CU.
// Writes bf16 agg row (norm_dst folded) into d_out-as-scratch.
__global__ __launch_bounds__(256) void gather_kernel(
    const short* __restrict__ fh, const int* __restrict__ csrOff,
    const int* __restrict__ srcSorted, const float* __restrict__ normIf,
    short* __restrict__ agg, int N) {
    int wv = threadIdx.x >> 6, lane = threadIdx.x & 63;
    int d = blockIdx.x * 4 + wv;
    if (d >= N) return;
    const ushort4* fh4 = (const ushort4*)fh;
    int beg = csrOff[d], end = csrOff[d + 1];
    float4 acc = make_float4(0.f, 0.f, 0.f, 0.f);
    #pragma unroll 8
    for (int e = beg; e < end; ++e) {
        int s = srcSorted[e];                     // wave-uniform scalar load
        ushort4 v = fh4[(size_t)s * 64 + lane];   // 8B/lane, 512B/wave
        acc.x += bf2f(v.x); acc.y += bf2f(v.y);
        acc.z += bf2f(v.z); acc.w += bf2f(v.w);
    }
    float nd = normIf[d];
    short4 p;
    p.x = f2bf(acc.x * nd); p.y = f2bf(acc.y * nd);
    p.z = f2bf(acc.z * nd); p.w = f2bf(acc.w * nd);
    *(short4*)&agg[(size_t)d * 256 + lane * 4] = p;
}

// ---------------------------------------------------------------------------
// K7: dense bf16 MFMA GEMM + GRU gates. Reads agg (bf16, aliased in d_out),
// writes f32 out to the SAME 512B-per-row span — block stages its own 64
// rows into LDS behind a barrier before any write, so no aliasing hazard.
__global__ __launch_bounds__(256, 4) void gemm_gates_kernel(
    const short* __restrict__ agg, const float* __restrict__ hx,
    const short* __restrict__ Wbf,
    const float* __restrict__ bi, const float* __restrict__ bh,
    float* __restrict__ out, int N) {
    __shared__ __align__(16) short sA[64 * 264];

    const int tid = threadIdx.x;
    const int wv = tid >> 6, lane = tid & 63;
    const int nb = blockIdx.x;
    const int nbase = nb * 64;

    // stage 64 rows x 512B, coalesced 16B units
    const int4* agg16 = (const int4*)agg;
    #pragma unroll
    for (int i = 0; i < 8; ++i) {
        int u = i * 256 + tid;          // 2048 units
        int r = u >> 5, c = u & 31;
        int row = nbase + r;
        int4 v = make_int4(0, 0, 0, 0);
        if (row < N) v = agg16[(size_t)row * 32 + c];
        *(int4*)&sA[r * 264 + c * 8] = v;
    }
    __syncthreads();

    const int l15 = lane & 15, quad = lane >> 4;
    const int wrb = wv * 16;
    const short* aRow = &sA[(wrb + l15) * 264];

    for (int cb = 0; cb < 8; ++cb) {
        f32x4v acc[6];
        #pragma unroll
        for (int g = 0; g < 6; ++g) acc[g] = (f32x4v){0.f, 0.f, 0.f, 0.f};

        #pragma unroll
        for (int kst = 0; kst < 4; ++kst) {
            const int ko = kst * 32 + quad * 8;
            bf16x8 aLo = *(const bf16x8*)&aRow[ko];
            bf16x8 aHi = *(const bf16x8*)&aRow[128 + ko];
            const short* wb = Wbf + cb * 12288 + l15 * 128 + ko;
            #pragma unroll
            for (int g = 0; g < 3; ++g) {
                bf16x8 bI = *(const bf16x8*)&wb[g * 2048];
                acc[g] = __builtin_amdgcn_mfma_f32_16x16x32_bf16(aLo, bI, acc[g], 0, 0, 0);
                bf16x8 bH = *(const bf16x8*)&wb[(g + 3) * 2048];
                acc[g + 3] = __builtin_amdgcn_mfma_f32_16x16x32_bf16(aHi, bH, acc[g + 3], 0, 0, 0);
            }
        }

        int ocol = cb * 16 + l15;
        float bir = bi[ocol], biz = bi[128 + ocol], bin = bi[256 + ocol];
        float bhr = bh[ocol], bhz = bh[128 + ocol], bhn = bh[256 + ocol];
        #pragma unroll
        for (int reg = 0; reg < 4; ++reg) {
            int row = nbase + wrb + quad * 4 + reg;
            if (row < N) {
                float ir = acc[0][reg] + bir, iz = acc[1][reg] + biz, in_ = acc[2][reg] + bin;
                float hr = acc[3][reg] + bhr, hz = acc[4][reg] + bhz, hn = acc[5][reg] + bhn;
                float rg = 1.0f / (1.0f + __expf(-(ir + hr)));
                float zg = 1.0f / (1.0f + __expf(-(iz + hz)));
                float ng = tanhf(in_ + rg * hn);
                float hv = hx[(size_t)row * DIM + ocol];
                out[(size_t)row * DIM + ocol] = (1.0f - zg) * ng + zg * hv;
            }
        }
    }
}

// ---------------------------------------------------------------------------
extern "C" void kernel_launch(void* const* d_in, const int* in_sizes, int n_in,
                              void* d_out, int out_size, void* d_ws, size_t ws_size,
                              hipStream_t stream) {
    const float* feat = (const float*)d_in[0];
    const float* hx   = (const float*)d_in[1];
    const float* Wi   = (const float*)d_in[2];
    const float* bi   = (const float*)d_in[3];
    const float* Wh   = (const float*)d_in[4];
    const float* bh   = (const float*)d_in[5];
    const int* src    = (const int*)d_in[6];
    const int* dst    = (const int*)d_in[7];
    float* out        = (float*)d_out;

    int N = in_sizes[0] / DIM;   // 50000
    int E = in_sizes[6];         // 800000
    int NB = (N + 1023) / 1024;  // 49 (<=64 required by the wave scan)

    int* wsi = (int*)d_ws;
    int* degO      = wsi;                      // N (degI contiguous after)
    int* degI      = wsi + N;                  // N
    int* csrOff    = wsi + 2 * N;              // N+1
    int* cursor    = wsi + 3 * N + 1;          // N+1
    int* srcSorted = wsi + 4 * N + 2;          // E
    int* bsum      = wsi + 4 * N + 2 + E;      // 64
    float* normIf  = (float*)(bsum + 128);     // N
    size_t wofs = (((size_t)(5 * N + 2 + E + 192)) * 4 + 15) & ~(size_t)15;
    short* Wbf = (short*)((char*)d_ws + wofs);         // 98304 bf16
    size_t fofs = (wofs + 98304 * 2 + 15) & ~(size_t)15;
    short* fh = (short*)((char*)d_ws + fofs);          // N*256 bf16 (~25.6MB)
    // total ws: ~30.1 MB (proven-safe budget: 51.6 MB)
    short* agg = (short*)d_out;  // bf16 agg aliased over d_out (see K7 note)

    hipMemsetAsync(degO, 0, (size_t)(2 * N) * sizeof(int), stream);
    k_deg<<<(E + 255) / 256, 256, 0, stream>>>(src, dst, degO, degI, E);
    k_bsum<<<NB, 256, 0, stream>>>(degI, bsum, N);
    k_off<<<NB, 256, 0, stream>>>(degI, bsum, csrOff, cursor, N, NB);
    k_xcw<<<(N * 65 + 98304 + 255) / 256, 256, 0, stream>>>(
        feat, hx, Wi, Wh, degO, degI, normIf, Wbf, fh, N);
    k_fill<<<(E + 255) / 256, 256, 0, stream>>>(src, dst, cursor, srcSorted, E);

    gather_kernel<<<(N + 3) / 4, 256, 0, stream>>>(
        fh, csrOff, srcSorted, normIf, agg, N);
    gemm_gates_kernel<<<(N + 63) / 64, 256, 0, stream>>>(
        agg, hx, Wbf, bi, bh, out, N);
}

// Round 9
// 383.481 us; speedup vs baseline: 3.3999x; 1.0180x over previous
//
#include <hip/hip_runtime.h>
#include <math.h>

#define DIM 128

typedef float f32x4v __attribute__((ext_vector_type(4)));
typedef short bf16x8 __attribute__((ext_vector_type(8)));

static __device__ __forceinline__ short f2bf(float f) {
    unsigned u = __float_as_uint(f);
    unsigned r = (u + 0x7fffu + ((u >> 16) & 1u)) >> 16;   // RNE
    return (short)r;
}
static __device__ __forceinline__ float bf2f(unsigned short s) {
    return __uint_as_float(((unsigned)s) << 16);
}

// ---------------------------------------------------------------------------
// K1: degree histogram with 4-way replicated counters to cut TCC same-line
// atomic contention. degR layout: [r*N+n] r=0..3 -> degO, r=4..7 -> degI.
__global__ __launch_bounds__(256) void k_deg(const int* __restrict__ src,
                                             const int* __restrict__ dst,
                                             int* degR, int N, int E) {
    int e = blockIdx.x * 256 + threadIdx.x;
    if (e < E) {
        int r = threadIdx.x & 3;
        atomicAdd(&degR[r * N + src[e]], 1);
        atomicAdd(&degR[(4 + r) * N + dst[e]], 1);
    }
}

// K2: per-1024-chunk sums of degI (over replicas).
__global__ __launch_bounds__(256) void k_bsum(const int* __restrict__ degR,
                                              int* __restrict__ bsum, int N) {
    __shared__ int red[4];
    int b = blockIdx.x, t = threadIdx.x;
    int idx = b * 1024 + t * 4;
    int s = 0;
    #pragma unroll
    for (int r = 4; r < 8; ++r) {
        const int* dI = degR + r * N;
        for (int j = 0; j < 4; ++j) if (idx + j < N) s += dI[idx + j];
    }
    for (int off = 32; off; off >>= 1) s += __shfl_down(s, off);
    if ((t & 63) == 0) red[t >> 6] = s;
    __syncthreads();
    if (t == 0) bsum[b] = red[0] + red[1] + red[2] + red[3];
}

// K3: per-chunk exclusive scan -> csrOff + cursor (wave 0 re-scans bsums).
__global__ __launch_bounds__(256) void k_off(const int* __restrict__ degR,
                                             const int* __restrict__ bsum,
                                             int* __restrict__ csrOff,
                                             int* __restrict__ cursor,
                                             int N, int NB) {
    __shared__ int sp[256];
    __shared__ int sbase;
    int b = blockIdx.x, t = threadIdx.x;
    if (t < 64) {
        int own = (t < NB) ? bsum[t] : 0;
        int v = own;
        for (int off = 1; off < 64; off <<= 1) {
            int u = __shfl_up(v, off);
            if (t >= off) v += u;
        }
        if (t == b) sbase = v - own;
        if (b == 0 && t == NB - 1) { csrOff[N] = v; cursor[N] = v; }
    }
    __syncthreads();
    int idx = b * 1024 + t * 4;
    int va[4] = {0, 0, 0, 0};
    #pragma unroll
    for (int r = 4; r < 8; ++r) {
        const int* dI = degR + r * N;
        for (int j = 0; j < 4; ++j) if (idx + j < N) va[j] += dI[idx + j];
    }
    int s = va[0] + va[1] + va[2] + va[3];
    sp[t] = s;
    __syncthreads();
    for (int off = 1; off < 256; off <<= 1) {
        int u = (t >= off) ? sp[t - off] : 0;
        __syncthreads();
        sp[t] += u;
        __syncthreads();
    }
    int o = sbase + sp[t] - s;
    for (int j = 0; j < 4; ++j) {
        if (idx + j < N) { csrOff[idx + j] = o; cursor[idx + j] = o; }
        o += va[j];
    }
}

// K4: merged normI + pre-scaled bf16 feat/hx + bf16 weight convert.
__global__ __launch_bounds__(256) void k_xcw(const float* __restrict__ feat,
                                             const float* __restrict__ hx,
                                             const float* __restrict__ Wi,
                                             const float* __restrict__ Wh,
                                             const int* __restrict__ degR,
                                             float* __restrict__ normIf,
                                             short* __restrict__ Wbf,
                                             short* __restrict__ fh, int N) {
    int i = blockIdx.x * 256 + threadIdx.x;
    int T1 = N * 64, T2 = N * 64 + N;
    if (i < T1) {
        int n = i >> 6, q = i & 63;
        int dO = degR[n] + degR[N + n] + degR[2 * N + n] + degR[3 * N + n];
        float ns = rsqrtf(fmaxf((float)dO, 1.0f));
        const float* spp = (q < 32) ? &feat[(size_t)n * 128 + q * 4]
                                    : &hx[(size_t)n * 128 + (q - 32) * 4];
        float4 v = *(const float4*)spp;
        short4 p;
        p.x = f2bf(v.x * ns); p.y = f2bf(v.y * ns);
        p.z = f2bf(v.z * ns); p.w = f2bf(v.w * ns);
        *(short4*)&fh[(size_t)n * 256 + q * 4] = p;   // q*4 == 128+(q-32)*4
    } else if (i < T2) {
        int n = i - T1;
        int dI = degR[4 * N + n] + degR[5 * N + n] + degR[6 * N + n] + degR[7 * N + n];
        normIf[n] = rsqrtf(fmaxf((float)dI, 1.0f));
    } else if (i < T2 + 98304) {
        int w = i - T2;
        int k = w & 127, n = (w >> 7) & 15, r = w >> 11;
        int gm = r % 6, cb = r / 6;
        const float* Wsrc = (gm < 3) ? Wi : Wh;
        int g = gm % 3;
        Wbf[w] = f2bf(Wsrc[k * 384 + g * 128 + cb * 16 + n]);
    }
}

// K5: counting-sort fill: srcSorted grouped by dst.
__global__ __launch_bounds__(256) void k_fill(const int* __restrict__ src,
                                              const int* __restrict__ dst,
                                              int* cursor, int* __restrict__ srcSorted,
                                              int E) {
    int e = blockIdx.x * 256 + threadIdx.x;
    if (e < E) {
        int pos = atomicAdd(&cursor[dst[e]], 1);
        srcSorted[pos] = src[e];
    }
}

// ---------------------------------------------------------------------------
// K6: gather-aggregate. One wave per dst node, no LDS -> high occupancy.
// Writes bf16 agg row (norm_dst folded) into d_out-as-scratch.
__global__ __launch_bounds__(256) void gather_kernel(
    const short* __restrict__ fh, const int* __restrict__ csrOff,
    const int* __restrict__ srcSorted, const float* __restrict__ normIf,
    short* __restrict__ agg, int N) {
    int wv = threadIdx.x >> 6, lane = threadIdx.x & 63;
    int d = blockIdx.x * 4 + wv;
    if (d >= N) return;
    const ushort4* fh4 = (const ushort4*)fh;
    int beg = csrOff[d], end = csrOff[d + 1];
    float4 acc = make_float4(0.f, 0.f, 0.f, 0.f);
    #pragma unroll 8
    for (int e = beg; e < end; ++e) {
        int s = srcSorted[e];                     // wave-uniform scalar load
        ushort4 v = fh4[(size_t)s * 64 + lane];   // 8B/lane, 512B/wave
        acc.x += bf2f(v.x); acc.y += bf2f(v.y);
        acc.z += bf2f(v.z); acc.w += bf2f(v.w);
    }
    float nd = normIf[d];
    short4 p;
    p.x = f2bf(acc.x * nd); p.y = f2bf(acc.y * nd);
    p.z = f2bf(acc.z * nd); p.w = f2bf(acc.w * nd);
    *(short4*)&agg[(size_t)d * 256 + lane * 4] = p;
}

// ---------------------------------------------------------------------------
// K7: dense bf16 MFMA GEMM + GRU gates, LDS-free. One wave per 16 rows.
// All A-fragments preloaded to registers BEFORE any out store (agg aliases
// out, but each wave only touches its own 16 rows -> no cross-wave hazard).
__global__ __launch_bounds__(256, 4) void gemm_gates_kernel(
    const short* __restrict__ agg, const float* __restrict__ hx,
    const short* __restrict__ Wbf,
    const float* __restrict__ bi, const float* __restrict__ bh,
    float* __restrict__ out, int N) {
    const int tid = threadIdx.x;
    const int wv = tid >> 6, lane = tid & 63;
    const int l15 = lane & 15, quad = lane >> 4;
    const int rowBase = (blockIdx.x * 4 + wv) * 16;
    if (rowBase >= N) return;
    int arow = rowBase + l15;
    if (arow >= N) arow = N - 1;           // safe clamp (value unused)
    const short* aPtr = agg + (size_t)arow * 256;

    bf16x8 aLo[4], aHi[4];
    #pragma unroll
    for (int kst = 0; kst < 4; ++kst) {
        aLo[kst] = *(const bf16x8*)&aPtr[kst * 32 + quad * 8];
        aHi[kst] = *(const bf16x8*)&aPtr[128 + kst * 32 + quad * 8];
    }

    for (int cb = 0; cb < 8; ++cb) {
        f32x4v acc[6];
        #pragma unroll
        for (int g = 0; g < 6; ++g) acc[g] = (f32x4v){0.f, 0.f, 0.f, 0.f};

        #pragma unroll
        for (int kst = 0; kst < 4; ++kst) {
            const short* wb = Wbf + cb * 12288 + l15 * 128 + kst * 32 + quad * 8;
            #pragma unroll
            for (int g = 0; g < 3; ++g) {
                bf16x8 bI = *(const bf16x8*)&wb[g * 2048];
                acc[g] = __builtin_amdgcn_mfma_f32_16x16x32_bf16(aLo[kst], bI, acc[g], 0, 0, 0);
                bf16x8 bH = *(const bf16x8*)&wb[(g + 3) * 2048];
                acc[g + 3] = __builtin_amdgcn_mfma_f32_16x16x32_bf16(aHi[kst], bH, acc[g + 3], 0, 0, 0);
            }
        }

        int ocol = cb * 16 + l15;
        float bir = bi[ocol], biz = bi[128 + ocol], bin = bi[256 + ocol];
        float bhr = bh[ocol], bhz = bh[128 + ocol], bhn = bh[256 + ocol];
        #pragma unroll
        for (int reg = 0; reg < 4; ++reg) {
            int row = rowBase + quad * 4 + reg;
            if (row < N) {
                float ir = acc[0][reg] + bir, iz = acc[1][reg] + biz, in_ = acc[2][reg] + bin;
                float hr = acc[3][reg] + bhr, hz = acc[4][reg] + bhz, hn = acc[5][reg] + bhn;
                float rg = 1.0f / (1.0f + __expf(-(ir + hr)));
                float zg = 1.0f / (1.0f + __expf(-(iz + hz)));
                float ng = tanhf(in_ + rg * hn);
                float hv = hx[(size_t)row * DIM + ocol];
                out[(size_t)row * DIM + ocol] = (1.0f - zg) * ng + zg * hv;
            }
        }
    }
}

// ---------------------------------------------------------------------------
extern "C" void kernel_launch(void* const* d_in, const int* in_sizes, int n_in,
                              void* d_out, int out_size, void* d_ws, size_t ws_size,
                              hipStream_t stream) {
    const float* feat = (const float*)d_in[0];
    const float* hx   = (const float*)d_in[1];
    const float* Wi   = (const float*)d_in[2];
    const float* bi   = (const float*)d_in[3];
    const float* Wh   = (const float*)d_in[4];
    const float* bh   = (const float*)d_in[5];
    const int* src    = (const int*)d_in[6];
    const int* dst    = (const int*)d_in[7];
    float* out        = (float*)d_out;

    int N = in_sizes[0] / DIM;   // 50000
    int E = in_sizes[6];         // 800000
    int NB = (N + 1023) / 1024;  // 49 (<=64 required by the wave scan)

    int* wsi = (int*)d_ws;
    int* degR      = wsi;                      // 8N (4 degO + 4 degI replicas)
    int* csrOff    = wsi + 8 * N;              // N+1
    int* cursor    = wsi + 9 * N + 1;          // N+1
    int* srcSorted = wsi + 10 * N + 2;         // E
    int* bsum      = wsi + 10 * N + 2 + E;     // 64
    float* normIf  = (float*)(bsum + 64);      // N
    size_t wofs = (((size_t)(11 * N + 2 + E + 64)) * 4 + 15) & ~(size_t)15;
    short* Wbf = (short*)((char*)d_ws + wofs);         // 98304 bf16
    size_t fofs = (wofs + 98304 * 2 + 15) & ~(size_t)15;
    short* fh = (short*)((char*)d_ws + fofs);          // N*256 bf16 (~25.6MB)
    // total ws: ~31.5 MB (proven-safe budget: 51.6 MB)
    short* agg = (short*)d_out;  // bf16 agg aliased over d_out

    hipMemsetAsync(degR, 0, (size_t)(8 * N) * sizeof(int), stream);
    k_deg<<<(E + 255) / 256, 256, 0, stream>>>(src, dst, degR, N, E);
    k_bsum<<<NB, 256, 0, stream>>>(degR, bsum, N);
    k_off<<<NB, 256, 0, stream>>>(degR, bsum, csrOff, cursor, N, NB);
    k_xcw<<<(N * 65 + 98304 + 255) / 256, 256, 0, stream>>>(
        feat, hx, Wi, Wh, degR, normIf, Wbf, fh, N);
    k_fill<<<(E + 255) / 256, 256, 0, stream>>>(src, dst, cursor, srcSorted, E);

    gather_kernel<<<(N + 3) / 4, 256, 0, stream>>>(
        fh, csrOff, srcSorted, normIf, agg, N);
    gemm_gates_kernel<<<((N + 15) / 16 + 3) / 4, 256, 0, stream>>>(
        agg, hx, Wbf, bi, bh, out, N);
}